// Round 1
// baseline (436.591 us; speedup 1.0000x reference)
//
#include <hip/hip_runtime.h>
#include <stdint.h>

// Problem constants (B=8,T=8192,C=256,E=64, top-2, cap_factor=1.25)
#define N_TOK   65536
#define S_SLOTS 131072
#define NEXP    64
#define CDIM    256
#define CAP     2560          // int(1.25 * 131072 / 64)
#define NCHUNK  1024          // 128 slots per chunk (= one gating block)

typedef unsigned short u16;
typedef float    fvec4  __attribute__((ext_vector_type(4)));
typedef float    f32x4  __attribute__((ext_vector_type(4)));
typedef __bf16   bf16x8 __attribute__((ext_vector_type(8)));
typedef unsigned short u16x4 __attribute__((ext_vector_type(4)));

typedef __attribute__((address_space(1))) const void gvoid_t;
typedef __attribute__((address_space(3))) void       svoid_t;

__device__ __forceinline__ u16 f2bf(float f) {          // RNE float->bf16
  uint32_t u = __builtin_bit_cast(uint32_t, f);
  u += 0x7fffu + ((u >> 16) & 1u);
  return (u16)(u >> 16);
}
__device__ __forceinline__ float bf2f(u16 h) {
  return __builtin_bit_cast(float, (uint32_t)h << 16);
}
__device__ __forceinline__ void gload16(const void* g, void* l) {
  __builtin_amdgcn_global_load_lds(
      reinterpret_cast<gvoid_t*>(reinterpret_cast<uintptr_t>(g)),
      reinterpret_cast<svoid_t*>(reinterpret_cast<uintptr_t>(l)),
      16, 0, 0);
}

// ---------------------------------------------------------------------------
// Kernel 1: gating (v2 — LDS-throughput rebalanced).
// 64-token x 64-expert tile, ONE wave (64 thr) per block, grid 1024 (chunk
// granularity unchanged -> scan/rank/downstream identical).
// 8x8 register blocking: 16 ds_read_b128 feed 256 FMAs (was 8 per 64).
// Staging via global_load_lds (width 16), double-buffered (T3 2-phase:
// issue next-tile loads BEFORE compute; syncthreads drain is then free).
// A tile uses XOR source-swizzle (chunk c of row r fetched from c^(r>>3))
// so the stride-8-row fragment reads hit 8 distinct bank groups.
// Tail (top2/softmax/load) fully in-register via 8-lane shfl butterflies.
// ---------------------------------------------------------------------------
__global__ __launch_bounds__(64) void gating_kernel(
    const float* __restrict__ x, const float* __restrict__ Wg,
    u16* __restrict__ x_bf16, float* __restrict__ slot_score,
    int* __restrict__ slot_eid, float* __restrict__ load_g,
    int* __restrict__ chunk_hist)
{
  // LDS: A dbuf 2x[64 rows][32 k] f32 = 16KB, W dbuf 2x[32 k][64 e] = 16KB.
  __shared__ float A_s[2][64 * 32];
  __shared__ float W_s[2][32 * 64];
  __shared__ int   hist_s[64];

  const int t  = threadIdx.x;            // 0..63 (single wave)
  const int m0 = blockIdx.x * 64;        // token tile base (== chunk id * 64)
  const int ty = t >> 3, tx = t & 7;     // 8x8 thread grid

  hist_s[t] = 0;

  float acc[8][8];
#pragma unroll
  for (int j = 0; j < 8; ++j)
#pragma unroll
    for (int i = 0; i < 8; ++i) acc[j][i] = 0.f;

  // ---- stage: A 512 chunks (16B), W 512 chunks; 8+8 gload16 per thread ----
  // A inst p: dest rows [p*8, p*8+8), lane reads global chunk (tx ^ p) of its
  // row (XOR swizzle, octet index == p is wave-uniform per inst).
  // W inst p: linear (rows k0+p*4 .. +4).
#define STAGE(B, K0)                                                          \
  {                                                                           \
    _Pragma("unroll")                                                         \
    for (int p = 0; p < 8; ++p)                                               \
      gload16(&x[(size_t)(m0 + p * 8 + ty) * 256 + (K0) + ((tx ^ p) << 2)],   \
              &A_s[B][p * 256]);                                              \
    _Pragma("unroll")                                                         \
    for (int p = 0; p < 8; ++p)                                               \
      gload16(&Wg[(size_t)((K0) + p * 4 + (t >> 4)) * 64 + (t & 15) * 4],     \
              &W_s[B][p * 256]);                                              \
  }

  STAGE(0, 0);
  __syncthreads();                       // drain prologue loads

  int buf = 0;
  for (int kt = 0; kt < 8; ++kt) {       // K = 256 in 8 chunks of 32
    if (kt < 7) {
      if (buf == 0) STAGE(1, (kt + 1) * 32) else STAGE(0, (kt + 1) * 32);
    }
    const float* Ab = A_s[buf];
    const float* Wb = W_s[buf];
#pragma unroll
    for (int k4 = 0; k4 < 8; ++k4) {
      fvec4 av[8];
#pragma unroll
      for (int j = 0; j < 8; ++j)        // row ty*8+j, swizzled chunk k4^ty
        av[j] = *(const fvec4*)&Ab[(ty * 8 + j) * 32 + ((k4 ^ ty) << 2)];
#pragma unroll
      for (int kk = 0; kk < 4; ++kk) {
        fvec4 b0 = *(const fvec4*)&Wb[(k4 * 4 + kk) * 64 + tx * 8];
        fvec4 b1 = *(const fvec4*)&Wb[(k4 * 4 + kk) * 64 + tx * 8 + 4];
#pragma unroll
        for (int j = 0; j < 8; ++j) {
          float a = av[j][kk];
          acc[j][0] = fmaf(a, b0.x, acc[j][0]);
          acc[j][1] = fmaf(a, b0.y, acc[j][1]);
          acc[j][2] = fmaf(a, b0.z, acc[j][2]);
          acc[j][3] = fmaf(a, b0.w, acc[j][3]);
          acc[j][4] = fmaf(a, b1.x, acc[j][4]);
          acc[j][5] = fmaf(a, b1.y, acc[j][5]);
          acc[j][6] = fmaf(a, b1.z, acc[j][6]);
          acc[j][7] = fmaf(a, b1.w, acc[j][7]);
        }
      }
    }
    __syncthreads();                     // drains next-tile vmcnt (free: loads
    buf ^= 1;                            // had the whole compute phase to fly)
  }
#undef STAGE

  // ---- x -> bf16 (separate coalesced pass; L2-hot re-read; RNE identical) --
  {
    const float* xb = x + (size_t)m0 * 256;
    u16* xh = x_bf16 + (size_t)m0 * 256;
#pragma unroll 8
    for (int p = 0; p < 64; ++p) {
      fvec4 v = *(const fvec4*)&xb[(p * 64 + t) * 4];
      u16x4 h;
      h.x = f2bf(v.x); h.y = f2bf(v.y); h.z = f2bf(v.z); h.w = f2bf(v.w);
      *(u16x4*)&xh[(p * 64 + t) * 4] = h;
    }
  }

  // ---- tail: per row j, 8 tx-lanes hold experts tx*8..tx*8+7 ----
  // top2 merge order: (value desc, index asc) == lax.top_k tie semantics.
  const int e0 = tx * 8;
  float pl[8];
#pragma unroll
  for (int i = 0; i < 8; ++i) pl[i] = 0.f;

#pragma unroll
  for (int j = 0; j < 8; ++j) {
    // local top2 over this lane's 8 experts (ascending e + strict '>')
    float v1 = -3.4e38f, v2 = -3.4e38f; int i1 = 0, i2 = 0;
#pragma unroll
    for (int i = 0; i < 8; ++i) {
      float lg = acc[j][i];
      if (lg > v1)      { v2 = v1; i2 = i1; v1 = lg; i1 = e0 + i; }
      else if (lg > v2) { v2 = lg; i2 = e0 + i; }
    }
    // butterfly merge across the 8 tx-lanes of this ty-group
#pragma unroll
    for (int off = 1; off < 8; off <<= 1) {
      float b1 = __shfl_xor(v1, off); int bi1 = __shfl_xor(i1, off);
      float b2 = __shfl_xor(v2, off); int bi2 = __shfl_xor(i2, off);
      bool w1 = (b1 > v1) || (b1 == v1 && bi1 < i1);
      if (w1) {
        bool k2 = (v1 > b2) || (v1 == b2 && i1 < bi2);
        v2 = k2 ? v1 : b2; i2 = k2 ? i1 : bi2;
        v1 = b1; i1 = bi1;
      } else {
        bool k2 = (b1 > v2) || (b1 == v2 && bi1 < i2);
        if (k2) { v2 = b1; i2 = bi1; }
      }
    }
    float m = v1;                        // top1 IS the row max
    // softmax denom + load partials
    float ex[8]; float s = 0.f;
#pragma unroll
    for (int i = 0; i < 8; ++i) { ex[i] = __expf(acc[j][i] - m); s += ex[i]; }
#pragma unroll
    for (int off = 1; off < 8; off <<= 1) s += __shfl_xor(s, off);
    float ri = 1.0f / s;
#pragma unroll
    for (int i = 0; i < 8; ++i) pl[i] = fmaf(ex[i], ri, pl[i]);

    if (tx == 0) {
      int tok = m0 + ty * 8 + j;
      slot_eid[2 * tok]     = i1;
      slot_eid[2 * tok + 1] = i2;
      slot_score[2 * tok]     = __expf(v1 - m) * ri;   // == 1*ri
      slot_score[2 * tok + 1] = __expf(v2 - m) * ri;
      atomicAdd(&hist_s[i1], 1);
      atomicAdd(&hist_s[i2], 1);
    }
  }

  // load partials: reduce over ty (lane bits 3..5); lanes t<8 own experts t*8+i
#pragma unroll
  for (int i = 0; i < 8; ++i) {
#pragma unroll
    for (int off = 8; off < 64; off <<= 1) pl[i] += __shfl_xor(pl[i], off);
  }
  if (t < 8) {
#pragma unroll
    for (int i = 0; i < 8; ++i) atomicAdd(&load_g[t * 8 + i], pl[i]);
  }

  __syncthreads();                       // order hist_s atomics vs read-back
  chunk_hist[blockIdx.x * 64 + t] = hist_s[t];
}

// ---------------------------------------------------------------------------
// Kernel 2: W_experts [e][k][d] fp32 -> WT [e][d][k] bf16 (K-fast for MFMA B).
// ---------------------------------------------------------------------------
__global__ __launch_bounds__(256) void wtrans_kernel(
    const float* __restrict__ W, u16* __restrict__ WT)
{
  __shared__ float tile[64 * 65];
  const int b = blockIdx.x;
  const int e = b >> 4, tt = b & 15;
  const int k0 = (tt >> 2) * 64, d0 = (tt & 3) * 64;
  const int t = threadIdx.x;
  const int j = t & 63, i0 = t >> 6;
  const float* We = W + (size_t)e * 65536;
#pragma unroll
  for (int p = 0; p < 16; ++p) {
    int i = p * 4 + i0;
    tile[i * 65 + j] = We[(size_t)(k0 + i) * 256 + d0 + j];   // coalesced on d
  }
  __syncthreads();
  u16* WTe = WT + (size_t)e * 65536;
#pragma unroll
  for (int p = 0; p < 16; ++p) {
    int d = p * 4 + i0;
    WTe[(size_t)(d0 + d) * 256 + k0 + j] = f2bf(tile[j * 65 + d]); // coalesced on k
  }
}

// ---------------------------------------------------------------------------
// Kernel 3a: per-expert exclusive scan over the 1024 chunk histograms.
// ---------------------------------------------------------------------------
__global__ __launch_bounds__(256) void scan_kernel(int* __restrict__ hist)
{
  const int e = blockIdx.x;
  const int t = threadIdx.x;
  const int lane = t & 63, w = t >> 6;
  int h[4];
#pragma unroll
  for (int i = 0; i < 4; ++i) h[i] = hist[(t * 4 + i) * 64 + e];
  int local = h[0] + h[1] + h[2] + h[3];
  int v = local;                         // inclusive wave scan
#pragma unroll
  for (int off = 1; off < 64; off <<= 1) {
    int u = __shfl_up(v, off);
    if (lane >= off) v += u;
  }
  __shared__ int wtot[4];
  if (lane == 63) wtot[w] = v;
  __syncthreads();
  int woff = 0;
  for (int i = 0; i < w; ++i) woff += wtot[i];
  int excl = woff + v - local;
  hist[(t * 4 + 0) * 64 + e] = excl;
  hist[(t * 4 + 1) * 64 + e] = excl + h[0];
  hist[(t * 4 + 2) * 64 + e] = excl + h[0] + h[1];
  hist[(t * 4 + 3) * 64 + e] = excl + h[0] + h[1] + h[2];
}

// ---------------------------------------------------------------------------
// Kernel 3b: rank. 1024 blocks x 128 thr (one slot each). Stable FIFO rank.
// ---------------------------------------------------------------------------
__global__ __launch_bounds__(128) void rank_kernel(
    const int* __restrict__ slot_eid, const int* __restrict__ base,
    int* __restrict__ slot2buf, int* __restrict__ row_token)
{
  const int c = blockIdx.x;
  const int t = threadIdx.x;
  const int s = c * 128 + t;
  const int lane = t & 63, w = t >> 6;
  const int e = slot_eid[s];
  __shared__ int hist0[64];
  if (t < 64) hist0[t] = 0;
  __syncthreads();
  int rank = 0, cnt = 0;
#pragma unroll
  for (int k = 0; k < 64; ++k) {
    int eo = __shfl(e, k);
    bool m = (eo == e);
    rank += (m && k < lane) ? 1 : 0;
    cnt  += m ? 1 : 0;
  }
  if (w == 0 && rank == cnt - 1) hist0[e] = cnt;   // last lane of its expert
  __syncthreads();
  int g = base[c * 64 + e] + rank + (w ? hist0[e] : 0);
  if (g < CAP) {
    slot2buf[s] = e * CAP + g;
    row_token[e * CAP + g] = s >> 1;
  } else {
    slot2buf[s] = -1;                               // capacity-dropped
  }
}

// ---------------------------------------------------------------------------
// Kernel 4: grouped expert GEMM, bf16 MFMA 16x16x32, 128x128 tile, BK=32,
// m97 structure with width-16 global_load_lds; A rows gathered via token ids.
// ---------------------------------------------------------------------------
__global__ __launch_bounds__(256) void gemm_kernel(
    const u16* __restrict__ x_bf16, const u16* __restrict__ WT,
    const int* __restrict__ row_token, u16* __restrict__ y)
{
  __shared__ u16 A_s[128 * 32];
  __shared__ u16 B_s[128 * 32];
  __shared__ int tok_s[128];

  const int b = blockIdx.x;
  const int e = b / 40;
  const int r = b % 40;
  const int m0 = (r >> 1) * 128, n0 = (r & 1) * 128;
  const int t = threadIdx.x;

  if (t < 128) tok_s[t] = row_token[e * CAP + m0 + t];
  __syncthreads();

  const int w = t >> 6, lane = t & 63;
  const int rsub = lane >> 2;
  const int koff = (lane & 3) * 8;

  const int ra0 = w * 32 + rsub;
  const int ra1 = ra0 + 16;
  const char* pa0 = (const char*)(x_bf16 + (size_t)tok_s[ra0] * 256 + koff);
  const char* pa1 = (const char*)(x_bf16 + (size_t)tok_s[ra1] * 256 + koff);
  const u16* WTe = WT + (size_t)e * 65536;
  const char* pb0 = (const char*)(WTe + (size_t)(n0 + ra0) * 256 + koff);
  const char* pb1 = (const char*)(WTe + (size_t)(n0 + ra1) * 256 + koff);

  char* ldsA0 = (char*)A_s + (w * 32) * 64;
  char* ldsA1 = (char*)A_s + (w * 32 + 16) * 64;
  char* ldsB0 = (char*)B_s + (w * 32) * 64;
  char* ldsB1 = (char*)B_s + (w * 32 + 16) * 64;

  const int wm = w & 1, wn = w >> 1;
  const int lr = lane & 15, q = lane >> 4;

  f32x4 acc[4][4];
#pragma unroll
  for (int mt = 0; mt < 4; ++mt)
#pragma unroll
    for (int nt = 0; nt < 4; ++nt) acc[mt][nt] = (f32x4){0.f, 0.f, 0.f, 0.f};

  for (int kt = 0; kt < 8; ++kt) {
    gload16(pa0, ldsA0);
    gload16(pa1, ldsA1);
    gload16(pb0, ldsB0);
    gload16(pb1, ldsB1);
    __syncthreads();
    bf16x8 af[4], bg[4];
#pragma unroll
    for (int mt = 0; mt < 4; ++mt)
      af[mt] = *(const bf16x8*)&A_s[(wm * 64 + mt * 16 + lr) * 32 + q * 8];
#pragma unroll
    for (int nt = 0; nt < 4; ++nt)
      bg[nt] = *(const bf16x8*)&B_s[(wn * 64 + nt * 16 + lr) * 32 + q * 8];
#pragma unroll
    for (int mt = 0; mt < 4; ++mt)
#pragma unroll
      for (int nt = 0; nt < 4; ++nt)
        acc[mt][nt] = __builtin_amdgcn_mfma_f32_16x16x32_bf16(
            af[mt], bg[nt], acc[mt][nt], 0, 0, 0);
    __syncthreads();
    pa0 += 64; pa1 += 64; pb0 += 64; pb1 += 64;
  }

  // C/D layout: col=lane&15, row=quad*4+reg  [verified m89/m91]
  u16* ye = y + (size_t)e * CAP * 256;
#pragma unroll
  for (int mt = 0; mt < 4; ++mt) {
    int grow = m0 + wm * 64 + mt * 16 + q * 4;
#pragma unroll
    for (int nt = 0; nt < 4; ++nt) {
      int gcol = n0 + wn * 64 + nt * 16 + lr;
#pragma unroll
      for (int rr = 0; rr < 4; ++rr)
        ye[(size_t)(grow + rr) * 256 + gcol] = f2bf(acc[mt][nt][rr]);
    }
  }
}

// ---------------------------------------------------------------------------
// Kernel 5: combine. out[t] = s0*y[p0] + s1*y[p1] (dropped -> 0). Wave/token.
// ---------------------------------------------------------------------------
__global__ __launch_bounds__(256) void combine_kernel(
    const u16* __restrict__ y, const int* __restrict__ slot2buf,
    const float* __restrict__ slot_score, float* __restrict__ out)
{
  const int tok  = blockIdx.x * 4 + (threadIdx.x >> 6);
  const int lane = threadIdx.x & 63;
  const int   p0 = slot2buf[2 * tok],   p1 = slot2buf[2 * tok + 1];
  const float s0 = slot_score[2 * tok], s1 = slot_score[2 * tok + 1];
  float o0 = 0.f, o1 = 0.f, o2 = 0.f, o3 = 0.f;
  if (p0 >= 0) {
    u16x4 h = *(const u16x4*)&y[(size_t)p0 * 256 + lane * 4];
    o0 = fmaf(s0, bf2f(h.x), o0); o1 = fmaf(s0, bf2f(h.y), o1);
    o2 = fmaf(s0, bf2f(h.z), o2); o3 = fmaf(s0, bf2f(h.w), o3);
  }
  if (p1 >= 0) {
    u16x4 h = *(const u16x4*)&y[(size_t)p1 * 256 + lane * 4];
    o0 = fmaf(s1, bf2f(h.x), o0); o1 = fmaf(s1, bf2f(h.y), o1);
    o2 = fmaf(s1, bf2f(h.z), o2); o3 = fmaf(s1, bf2f(h.w), o3);
  }
  fvec4 o = {o0, o1, o2, o3};
  *(fvec4*)&out[(size_t)tok * 256 + lane * 4] = o;
}

// ---------------------------------------------------------------------------
// Kernel 6: aux loss = mean((load/N - 1/E)^2). One wave.
// ---------------------------------------------------------------------------
__global__ __launch_bounds__(64) void aux_kernel(
    const float* __restrict__ load_g, float* __restrict__ out_aux)
{
  const int lane = threadIdx.x;
  float l = load_g[lane] * (1.0f / 65536.0f) - (1.0f / 64.0f);
  float v = l * l;
#pragma unroll
  for (int off = 1; off < 64; off <<= 1) v += __shfl_xor(v, off);
  if (lane == 0) out_aux[0] = v * (1.0f / 64.0f);
}

// ---------------------------------------------------------------------------
// Workspace layout (bytes):
//   0        slot_score f32[131072]   (512K)
//   524288   slot_eid   i32[131072]   (512K)
//   1048576  slot2buf   i32[131072]   (512K)
//   1572864  row_token  i32[163840]   (640K)  -- memset 0 each call
//   2228224  load_g     f32[64]               -- memset 0 each call
//   2359296  chunk_hist i32[1024*64]  (256K)  -- fully written by gating
//   4194304  x_bf16     u16[16777216] (32M)
//   37748736 WT         u16[4194304]  (8M)
//   46137344 y          u16[41943040] (80M)
// total ~124 MB
// ---------------------------------------------------------------------------
extern "C" void kernel_launch(void* const* d_in, const int* in_sizes, int n_in,
                              void* d_out, int out_size, void* d_ws, size_t ws_size,
                              hipStream_t stream)
{
  const float* x  = (const float*)d_in[0];
  const float* Wg = (const float*)d_in[1];
  const float* We = (const float*)d_in[2];
  float* out = (float*)d_out;

  char* ws = (char*)d_ws;
  float* slot_score = (float*)(ws + 0);
  int*   slot_eid   = (int*)(ws + 524288);
  int*   slot2buf   = (int*)(ws + 1048576);
  int*   row_token  = (int*)(ws + 1572864);
  float* load_g     = (float*)(ws + 2228224);
  int*   chunk_hist = (int*)(ws + 2359296);
  u16*   x_bf16     = (u16*)(ws + 4194304);
  u16*   WT         = (u16*)(ws + 37748736);
  u16*   y          = (u16*)(ws + 46137344);

  hipMemsetAsync(row_token, 0, 655360, stream);   // unfilled rows -> token 0
  hipMemsetAsync(load_g, 0, 256, stream);

  gating_kernel<<<1024, 64, 0, stream>>>(x, Wg, x_bf16, slot_score, slot_eid,
                                         load_g, chunk_hist);
  wtrans_kernel<<<1024, 256, 0, stream>>>(We, WT);
  scan_kernel<<<64, 256, 0, stream>>>(chunk_hist);
  rank_kernel<<<1024, 128, 0, stream>>>(slot_eid, chunk_hist, slot2buf, row_token);
  gemm_kernel<<<2560, 256, 0, stream>>>(x_bf16, WT, row_token, y);
  combine_kernel<<<16384, 256, 0, stream>>>(y, slot2buf, slot_score, out);
  aux_kernel<<<1, 64, 0, stream>>>(load_g, out + 16777216);
}